// Round 18
// baseline (491.820 us; speedup 1.0000x reference)
//
#include <hip/hip_runtime.h>
#include <math.h>
#include <type_traits>
#include <utility>

#define TT 2048
typedef unsigned short u16;
typedef unsigned int u32;
typedef float f32x4 __attribute__((ext_vector_type(4)));
typedef float f32x16 __attribute__((ext_vector_type(16)));
typedef short s16x8 __attribute__((ext_vector_type(8)));
typedef __bf16 bf16x8 __attribute__((ext_vector_type(8)));
typedef __bf16 bf16x2 __attribute__((ext_vector_type(2)));
typedef u32 u32x4 __attribute__((ext_vector_type(4)));

#define L2E8 0.1803368801111731f   // 0.125 * log2(e)
#define EXP2(x) __builtin_amdgcn_exp2f(x)   // raw v_exp_f32 (glibc-macro-safe)

enum { EPI_PE = 0, EPI_QKV = 1, EPI_RES = 2, EPI_GELU = 3, EPI_OUTF = 4 };

// ---- MFMA wrappers: handle either builtin signature (v8i16 or v8bf16) ----
template<typename V, typename = void> struct mfma32_takes : std::false_type {};
template<typename V> struct mfma32_takes<V, std::void_t<decltype(
    __builtin_amdgcn_mfma_f32_32x32x16_bf16(std::declval<V>(), std::declval<V>(),
                                            std::declval<f32x16>(), 0, 0, 0))>>
    : std::true_type {};

template<typename VA>
__device__ __forceinline__ f32x16 MFMA32(VA a, VA b, f32x16 c) {
    if constexpr (mfma32_takes<VA>::value) {
        return __builtin_amdgcn_mfma_f32_32x32x16_bf16(a, b, c, 0, 0, 0);
    } else {
        return __builtin_amdgcn_mfma_f32_32x32x16_bf16(
            __builtin_bit_cast(bf16x8, a), __builtin_bit_cast(bf16x8, b), c, 0, 0, 0);
    }
}

// fp32 -> bf16 RNE
__device__ __forceinline__ u16 f2b(float f) {
    u32 u = __float_as_uint(f);
    return (u16)((u + 0x7FFFu + ((u >> 16) & 1u)) >> 16);
}

__device__ __forceinline__ u32 pkbf(float a, float b) {
    bf16x2 t; t[0] = (__bf16)a; t[1] = (__bf16)b;
    return __builtin_bit_cast(u32, t);
}

// async global->LDS, 16B per lane; LDS dest = uniform base + lane*16
__device__ __forceinline__ void gload16(const void* g, void* lds_base, int lds_byte_off) {
    __builtin_amdgcn_global_load_lds(
        (const __attribute__((address_space(1))) void*)g,
        (__attribute__((address_space(3))) void*)((char*)lds_base + lds_byte_off),
        16, 0, 0);
}

// gelu via tanh form: max dev ~3e-4 from exact (<< bf16 ulp here)
__device__ __forceinline__ float gelu_f(float v) {
    const float u = v * (1.f + 0.044715f * v * v) * 0.7978845608028654f;
    const float e = EXP2(u * 2.885390081777927f);   // e^{2u}
    const float th = 1.f - 2.f * __builtin_amdgcn_rcpf(e + 1.f);
    return 0.5f * v * (1.f + th);
}

// ---------------------------------------------------------------------------
// bf16 MFMA GEMM (1-phase, 32x32x16 frags): C = A[M,K] @ Bt[N,K]^T + bias.
// XCD-aware block swizzle (T1): work = (p&7)*(nwg/8) + (p>>3) so each XCD's
// L2 owns a contiguous y-range. Bijective since all grids are multiples of 8.
// Tile TM x TN, BK=64, 4 waves (2x2); wave = TM/2 x TN/2 in 32x32 frags.
// C/D map: col=l&31, row=(reg&3)+8*(reg>>2)+4*(l>>5) (m101-verified).
// EPI_QKV: Q cols -> big; K cols -> Kf frag-native; V cols -> LDS-transposed
// into Vf. K/V cols are NOT written to big.
// ---------------------------------------------------------------------------
template<int EPI, int TM, int TN>
__global__ __launch_bounds__(256)
void k_gemm_mfma(const u16* __restrict__ A, const u16* __restrict__ Bt,
                 const float* __restrict__ bias, const float* __restrict__ Rf,
                 void* __restrict__ Cout, u16* __restrict__ Kfp,
                 u16* __restrict__ Vfp, int M, int N, int K)
{
    constexpr int MF = TM / 64;                 // 32x32 m-frags per wave
    constexpr int NF = TN / 64;                 // 32x32 n-frags per wave
    __shared__ __attribute__((aligned(16))) u16 SMEM[TM * 64 + TN * 64];
    u16* As = SMEM;
    u16* Bs = SMEM + TM * 64;
    const int tid = threadIdx.x;
    const int l = tid & 63, wv = tid >> 6;
    const int l31 = l & 31, hi = l >> 5;
    const int wr = wv >> 1, wc = wv & 1;

    // XCD-aware swizzle of the linear block id
    const int gx = gridDim.x;
    const int nwg = gx * gridDim.y;
    int bid = blockIdx.y * gx + blockIdx.x;
    if ((nwg & 7) == 0) bid = (bid & 7) * (nwg >> 3) + (bid >> 3);
    const int bxi = bid % gx, byi = bid / gx;
    const int row0 = byi * TM, col0 = bxi * TN;

    f32x16 acc[MF][NF] = {};

    for (int kt = 0; kt < K; kt += 64) {
#pragma unroll
        for (int i = 0; i < TM / 32; ++i) {          // A: TM*8 chunks of 16B
            const int u = i * 256 + wv * 64 + l;
            const int ar = u >> 3, ac = u & 7;
            const int sc = (ac ^ (ar & 7)) << 3;     // source chunk *8 elems
            const int off = __builtin_amdgcn_readfirstlane((i * 256 + wv * 64) * 16);
            gload16(A + (size_t)(row0 + ar) * K + kt + sc, As, off);
        }
#pragma unroll
        for (int i = 0; i < TN / 32; ++i) {          // B: TN*8 chunks
            const int u = i * 256 + wv * 64 + l;
            const int ar = u >> 3, ac = u & 7;
            const int sc = (ac ^ (ar & 7)) << 3;
            const int off = __builtin_amdgcn_readfirstlane((i * 256 + wv * 64) * 16);
            gload16(Bt + (size_t)(col0 + ar) * K + kt + sc, Bs, off);
        }
        __syncthreads();
        s16x8 af[MF][4], bf[NF][4];
#pragma unroll
        for (int m = 0; m < MF; ++m) {
            const int r = wr * (TM / 2) + m * 32 + l31;
#pragma unroll
            for (int kk = 0; kk < 4; ++kk)
                af[m][kk] = *(const s16x8*)(As + r * 64 + (((kk * 2 + hi) ^ (r & 7)) << 3));
        }
#pragma unroll
        for (int n = 0; n < NF; ++n) {
            const int r = wc * (TN / 2) + n * 32 + l31;
#pragma unroll
            for (int kk = 0; kk < 4; ++kk)
                bf[n][kk] = *(const s16x8*)(Bs + r * 64 + (((kk * 2 + hi) ^ (r & 7)) << 3));
        }
#pragma unroll
        for (int kk = 0; kk < 4; ++kk)
#pragma unroll
            for (int m = 0; m < MF; ++m)
#pragma unroll
                for (int n = 0; n < NF; ++n)
                    acc[m][n] = MFMA32(af[m][kk], bf[n][kk], acc[m][n]);
        __syncthreads();
    }

    if constexpr (EPI == EPI_QKV) {
        if (col0 < 512) {
            // ---- Q region: bf16 to big
#pragma unroll
            for (int m = 0; m < MF; ++m)
#pragma unroll
                for (int r = 0; r < 16; ++r) {
                    const int row = row0 + wr * (TM / 2) + m * 32 + (r & 3) + 8 * (r >> 2) + 4 * hi;
#pragma unroll
                    for (int n = 0; n < NF; ++n) {
                        const int col = col0 + wc * (TN / 2) + n * 32 + l31;
                        ((u16*)Cout)[(size_t)row * N + col] = f2b(acc[m][n][r] + bias[col]);
                    }
                }
        } else if (col0 < 1024) {
            // ---- K region: frag-native Kf direct
#pragma unroll
            for (int m = 0; m < MF; ++m)
#pragma unroll
                for (int r = 0; r < 16; ++r) {
                    const int row = row0 + wr * (TM / 2) + m * 32 + (r & 3) + 8 * (r >> 2) + 4 * hi;
                    const int t = row & (TT - 1), bb = row >> 11;
#pragma unroll
                    for (int n = 0; n < NF; ++n) {
                        const int col = col0 + wc * (TN / 2) + n * 32 + l31;
                        const int dd = col - 512;
                        const int hh = dd >> 6, c = (dd >> 3) & 7, j = dd & 7;
                        Kfp[(((size_t)(bb * 8 + hh) * 8 + c) * 2048 + t) * 8 + j]
                            = f2b(acc[m][n][r] + bias[col]);
                    }
                }
        } else {
            // ---- V region: transpose via LDS -> Vf (coalesced uint4)
            u16* TV = SMEM;                      // [64][128], reuse staging LDS
#pragma unroll
            for (int m = 0; m < MF; ++m)
#pragma unroll
                for (int r = 0; r < 16; ++r) {
                    const int rr = wr * (TM / 2) + m * 32 + (r & 3) + 8 * (r >> 2) + 4 * hi;
#pragma unroll
                    for (int n = 0; n < NF; ++n) {
                        const int cc_ = wc * (TN / 2) + n * 32 + l31;
                        TV[rr * 128 + cc_] = f2b(acc[m][n][r] + bias[col0 + cc_]);
                    }
                }
            __syncthreads();
            const int gt = (row0 & (TT - 1)) >> 6, bb = row0 >> 11;
            const int hh0 = (col0 - 1024) >> 6;
#pragma unroll
            for (int i = 0; i < 4; ++i) {
                const int u = i * 256 + tid;
                const int hsel = u >> 9, rem = u & 511;
                const int cc = rem >> 6, d = rem & 63;
                u32 pk[4];
#pragma unroll
                for (int jp = 0; jp < 4; ++jp)
                    pk[jp] = (u32)TV[(cc * 8 + 2 * jp) * 128 + hsel * 64 + d]
                           | ((u32)TV[(cc * 8 + 2 * jp + 1) * 128 + hsel * 64 + d] << 16);
                *(uint4*)(Vfp + ((((size_t)(bb * 8 + hh0 + hsel) * 32 + gt) * 8 + cc) * 64 + d) * 8)
                    = make_uint4(pk[0], pk[1], pk[2], pk[3]);
            }
        }
        return;
    }

#pragma unroll
    for (int m = 0; m < MF; ++m)
#pragma unroll
        for (int r = 0; r < 16; ++r) {
            const int row = row0 + wr * (TM / 2) + m * 32 + (r & 3) + 8 * (r >> 2) + 4 * hi;
#pragma unroll
            for (int n = 0; n < NF; ++n) {
                const int col = col0 + wc * (TN / 2) + n * 32 + l31;
                float v = acc[m][n][r] + bias[col];
                const size_t idx = (size_t)row * N + col;
                if constexpr (EPI == EPI_PE) {
                    const int t = row & (TT - 1);
                    const float freq = __expf(-(float)(col & ~1) * 0.017988946039015984f);
                    const float ang = (float)t * freq;
                    v += (col & 1) ? cosf(ang) : sinf(ang);
                    ((float*)Cout)[idx] = v;
                } else if constexpr (EPI == EPI_GELU) {
                    ((u16*)Cout)[idx] = f2b(gelu_f(v));
                } else if constexpr (EPI == EPI_RES) {
                    ((float*)Cout)[idx] = Rf[idx] + v;
                } else {
                    ((float*)Cout)[idx] = v;
                }
            }
        }
}

// ---------------------------------------------------------------------------
// LayerNorm D=512: h(fp32) -> y(bf16). One wave per row.
// ---------------------------------------------------------------------------
__global__ __launch_bounds__(256)
void k_ln(const float* __restrict__ X, const float* __restrict__ g,
          const float* __restrict__ b, u16* __restrict__ Y)
{
    const int lane = threadIdx.x & 63;
    const int row = blockIdx.x * 4 + (threadIdx.x >> 6);
    const float* x = X + (size_t)row * 512 + lane * 8;

    float4 v0 = *(const float4*)x;
    float4 v1 = *(const float4*)(x + 4);
    float vals[8] = {v0.x, v0.y, v0.z, v0.w, v1.x, v1.y, v1.z, v1.w};

    float s = 0.f;
#pragma unroll
    for (int i = 0; i < 8; ++i) s += vals[i];
#pragma unroll
    for (int off = 32; off >= 1; off >>= 1) s += __shfl_xor(s, off);
    const float mu = s * (1.f / 512.f);

    float sq = 0.f;
#pragma unroll
    for (int i = 0; i < 8; ++i) { float d = vals[i] - mu; sq += d * d; }
#pragma unroll
    for (int off = 32; off >= 1; off >>= 1) sq += __shfl_xor(sq, off);
    const float rs = rsqrtf(sq * (1.f / 512.f) + 1e-5f);

    const float* gp = g + lane * 8;
    const float* bp = b + lane * 8;
    float4 g0 = *(const float4*)gp, g1 = *(const float4*)(gp + 4);
    float4 b0 = *(const float4*)bp, b1 = *(const float4*)(bp + 4);
    float ga[8] = {g0.x, g0.y, g0.z, g0.w, g1.x, g1.y, g1.z, g1.w};
    float bb[8] = {b0.x, b0.y, b0.z, b0.w, b1.x, b1.y, b1.z, b1.w};

    u32 pk[4];
#pragma unroll
    for (int i = 0; i < 4; ++i) {
        float a0 = (vals[2 * i]     - mu) * rs * ga[2 * i]     + bb[2 * i];
        float a1 = (vals[2 * i + 1] - mu) * rs * ga[2 * i + 1] + bb[2 * i + 1];
        pk[i] = (u32)f2b(a0) | ((u32)f2b(a1) << 16);
    }
    *(uint4*)(Y + (size_t)row * 512 + lane * 8) = make_uint4(pk[0], pk[1], pk[2], pk[3]);
}

// ---------------------------------------------------------------------------
// Causal flash attention, in-block split-KV, FRAGMENT-NATIVE K/V loads.
// V-frags hoisted to the top of the kv-loop (issue-early: ~300cy L2 latency
// hides under QK^T + softmax + repack). exp2 softmax + setprio. (else r14)
// ---------------------------------------------------------------------------
__global__ __launch_bounds__(256, 4)
void k_attn(const u16* __restrict__ qkv, const u16* __restrict__ Kf,
            const u16* __restrict__ Vf, u16* __restrict__ y)
{
    __shared__ float Om[4][32 * 65];     // [wave][q*65 + d]
    __shared__ float Ml[4][32][2];       // [wave][q][{m,l}]
    const int tid = threadIdx.x;
    const int l = tid & 63, w = tid >> 6;
    const int l31 = l & 31, hi = l >> 5;
    const int bx = blockIdx.x;
    const int xcd = bx & 7, s = bx >> 3;
    const int bh = xcd * 2 + (s & 1);
    const int t_tile = 63 - (s >> 1);
    const int b = bh >> 3, hh = bh & 7;
    const int bT = b * TT, hh64 = hh * 64;

    const int qg = t_tile * 32 + l31;
    const int NT = (t_tile >> 1) + 1;    // kv tiles (64-wide) this q-tile needs

    f32x16 o[2] = {};
    float m = -1e30f, lsum = 0.f;

    if (w < NT) {
        // Q B-frags (scattered, but once per wave)
        s16x8 qf[4];
        {
            const u16* qsrc = qkv + (size_t)(bT + qg) * 1536 + hh64 + hi * 8;
#pragma unroll
            for (int dk = 0; dk < 4; ++dk) qf[dk] = *(const s16x8*)(qsrc + dk * 16);
        }
        const u16* kfb = Kf + ((size_t)bh * 8 + hi) * 2048 * 8;
        const u16* vfb = Vf + (((size_t)bh * 32) * 8 + hi) * 64 * 8;

        for (int g = w; g < NT; g += 4) {
            // K frags + V frags issued together: 16 loads in flight, V's
            // latency covered by QK^T + softmax + repack
            s16x8 kf[8], vf[8];
#pragma unroll
            for (int nb = 0; nb < 2; ++nb)
#pragma unroll
                for (int dk = 0; dk < 4; ++dk)
                    kf[nb * 4 + dk] = *(const s16x8*)(
                        kfb + ((size_t)(dk * 2) * 2048 + g * 64 + nb * 32 + l31) * 8);
#pragma unroll
            for (int dt = 0; dt < 2; ++dt)
#pragma unroll
                for (int ks = 0; ks < 4; ++ks)
                    vf[dt * 4 + ks] = *(const s16x8*)(
                        vfb + (((size_t)g * 8 + ks * 2) * 64 + dt * 32 + l31) * 8);

            // S^T = K Q^T over d=64
            f32x16 sA[2];
            __builtin_amdgcn_s_setprio(1);
#pragma unroll
            for (int nb = 0; nb < 2; ++nb) {
                f32x16 acc = {};
#pragma unroll
                for (int dk = 0; dk < 4; ++dk) acc = MFMA32(kf[nb * 4 + dk], qf[dk], acc);
                sA[nb] = acc;
            }
            __builtin_amdgcn_s_setprio(0);

            // causal mask on the diagonal supertile
            if (g == NT - 1) {
                const int kvb = g * 64, hi4 = hi * 4;
#pragma unroll
                for (int nb = 0; nb < 2; ++nb)
#pragma unroll
                    for (int r = 0; r < 16; ++r) {
                        const int kv = kvb + nb * 32 + (r & 3) + 8 * (r >> 2) + hi4;
                        sA[nb][r] = (kv > qg) ? -1e30f : sA[nb][r];
                    }
            }

            // online softmax (scale*log2e folded into exp2), exact defer-max
            float tmp[16];
#pragma unroll
            for (int r = 0; r < 16; ++r) tmp[r] = fmaxf(sA[0][r], sA[1][r]);
#pragma unroll
            for (int st = 8; st >= 1; st >>= 1)
#pragma unroll
                for (int r = 0; r < 8; ++r)
                    if (r < st) tmp[r] = fmaxf(tmp[r], tmp[r + st]);
            float mt = fmaxf(tmp[0], __shfl_xor(tmp[0], 32));
            const bool grow = !__all(mt <= m);
            if (grow) {
                const float mn = fmaxf(m, mt);
                const float alpha = EXP2((m - mn) * L2E8);
                m = mn;
                lsum *= alpha;
#pragma unroll
                for (int dt = 0; dt < 2; ++dt)
#pragma unroll
                    for (int r = 0; r < 16; ++r) o[dt][r] *= alpha;
            }
            const float mc = -m * L2E8;

            float p[2][16];
            float sum[16];
#pragma unroll
            for (int r = 0; r < 16; ++r) {
                p[0][r] = EXP2(fmaf(sA[0][r], L2E8, mc));
                p[1][r] = EXP2(fmaf(sA[1][r], L2E8, mc));
                sum[r] = p[0][r] + p[1][r];
            }
#pragma unroll
            for (int st = 8; st >= 1; st >>= 1)
#pragma unroll
                for (int r = 0; r < 8; ++r)
                    if (r < st) sum[r] += sum[r + st];
            float psum = sum[0] + __shfl_xor(sum[0], 32);
            lsum += psum;

            // P (f32, D-layout) -> bf16 A-frags via lane<->lane+32 exchange
            u32 pk2[2][8], sw2[2][8];
#pragma unroll
            for (int nb = 0; nb < 2; ++nb)
#pragma unroll
                for (int i = 0; i < 8; ++i) {
                    pk2[nb][i] = pkbf(p[nb][2 * i], p[nb][2 * i + 1]);
                    sw2[nb][i] = __shfl_xor(pk2[nb][i], 32);
                }
            s16x8 pa[4];
#pragma unroll
            for (int nb = 0; nb < 2; ++nb)
#pragma unroll
                for (int k16 = 0; k16 < 2; ++k16) {
                    const int i0 = k16 * 4;
                    u32 w0 = hi ? sw2[nb][i0 + 2] : pk2[nb][i0 + 0];
                    u32 w1 = hi ? sw2[nb][i0 + 3] : pk2[nb][i0 + 1];
                    u32 w2 = hi ? pk2[nb][i0 + 2] : sw2[nb][i0 + 0];
                    u32 w3 = hi ? pk2[nb][i0 + 3] : sw2[nb][i0 + 1];
                    u32x4 t4 = {w0, w1, w2, w3};
                    pa[nb * 2 + k16] = __builtin_bit_cast(s16x8, t4);
                }

            // O^T += V^T P^T (V already in registers)
            __builtin_amdgcn_s_setprio(1);
#pragma unroll
            for (int dt = 0; dt < 2; ++dt) {
                f32x16 acc = o[dt];
#pragma unroll
                for (int ks = 0; ks < 4; ++ks)
                    acc = MFMA32(vf[dt * 4 + ks], pa[ks], acc);
                o[dt] = acc;
            }
            __builtin_amdgcn_s_setprio(0);
        }
    }

    // ---- dump partials: lane q = l31, d = dt*32 + (r&3)+8*(r>>2)+4*hi
#pragma unroll
    for (int dt = 0; dt < 2; ++dt)
#pragma unroll
        for (int r = 0; r < 16; ++r) {
            const int d = dt * 32 + (r & 3) + 8 * (r >> 2) + 4 * hi;
            Om[w][l31 * 65 + d] = o[dt][r];
        }
    Ml[w][l31][0] = m;
    Ml[w][l31][1] = lsum;
    __syncthreads();

    // ---- combine: thread -> (q = tid&31, d-range (tid>>5)*8 .. +7)
    const int q = tid & 31, d0 = (tid >> 5) * 8;
    float m0 = Ml[0][q][0], m1 = Ml[1][q][0], m2 = Ml[2][q][0], m3 = Ml[3][q][0];
    const float mstar = fmaxf(fmaxf(m0, m1), fmaxf(m2, m3));
    float sc[4];
    sc[0] = EXP2((m0 - mstar) * L2E8);
    sc[1] = EXP2((m1 - mstar) * L2E8);
    sc[2] = EXP2((m2 - mstar) * L2E8);
    sc[3] = EXP2((m3 - mstar) * L2E8);
    const float lstar = sc[0] * Ml[0][q][1] + sc[1] * Ml[1][q][1]
                      + sc[2] * Ml[2][q][1] + sc[3] * Ml[3][q][1];
    float ov[8];
#pragma unroll
    for (int j = 0; j < 8; ++j) ov[j] = 0.f;
#pragma unroll
    for (int ww = 0; ww < 4; ++ww) {
        const float scw = sc[ww];
        const float* src = &Om[ww][q * 65 + d0];
#pragma unroll
        for (int j = 0; j < 8; ++j) ov[j] = fmaf(scw, src[j], ov[j]);
    }
    const float inv = 1.f / lstar;
    u32 pk[4];
#pragma unroll
    for (int i = 0; i < 4; ++i) pk[i] = pkbf(ov[2 * i] * inv, ov[2 * i + 1] * inv);
    u16* yp = y + (size_t)(bT + t_tile * 32 + q) * 512 + hh64 + d0;
    *(uint4*)yp = make_uint4(pk[0], pk[1], pk[2], pk[3]);
}

// ---------------------------------------------------------------------------
// ALL-layer LDS-tiled weight transpose fp32[K][N] -> bf16[N][K], 64x64 tiles.
// One launch: 3072 blocks (4 layers x 768) + 16 Win + 16 Wout = 3104.
// ---------------------------------------------------------------------------
__global__ __launch_bounds__(256)
void k_wt_all(const float* __restrict__ Wqkv, const float* __restrict__ Wo,
              const float* __restrict__ Wf1, const float* __restrict__ Wf2,
              const float* __restrict__ Win, const float* __restrict__ Wout,
              u16* __restrict__ WqkvT, u16* __restrict__ WoT,
              u16* __restrict__ Wf1T, u16* __restrict__ Wf2T,
              u16* __restrict__ WinT, u16* __restrict__ WoutT)
{
    __shared__ float T[64][65];
    const int tid = threadIdx.x;
    int id = blockIdx.x;
    const float* W; u16* Wt; int K, N;
    if (id < 3072) {
        const int lyr = id / 768, sub = id - lyr * 768;
        if (sub < 192)      { W = Wqkv + (size_t)lyr * 512 * 1536; Wt = WqkvT + (size_t)lyr * 512 * 1536; K = 512;  N = 1536; id = sub; }
        else if (sub < 256) { W = Wo   + (size_t)lyr * 512 * 512;  Wt = WoT   + (size_t)lyr * 512 * 512;  K = 512;  N = 512;  id = sub - 192; }
        else if (sub < 512) { W = Wf1  + (size_t)lyr * 512 * 2048; Wt = Wf1T  + (size_t)lyr * 512 * 2048; K = 512;  N = 2048; id = sub - 256; }
        else                { W = Wf2  + (size_t)lyr * 2048 * 512; Wt = Wf2T  + (size_t)lyr * 2048 * 512; K = 2048; N = 512;  id = sub - 512; }
    } else if (id < 3088)   { W = Win;  Wt = WinT;  K = 128; N = 512; id -= 3072; }
    else                    { W = Wout; Wt = WoutT; K = 512; N = 128; id -= 3088; }
    const int nt = N >> 6;
    const int ktile = id / nt, ntile = id - ktile * nt;
    const int kb = ktile * 64, nb = ntile * 64;
#pragma unroll
    for (int i = 0; i < 4; ++i) {
        const int r = i * 16 + (tid >> 4), c = (tid & 15) * 4;
        const float4 v = *(const float4*)&W[(size_t)(kb + r) * N + nb + c];
        T[r][c] = v.x; T[r][c + 1] = v.y; T[r][c + 2] = v.z; T[r][c + 3] = v.w;
    }
    __syncthreads();
    const int n = tid >> 2, k0 = (tid & 3) * 16;
    u32 pk[8];
#pragma unroll
    for (int i = 0; i < 8; ++i)
        pk[i] = pkbf(T[k0 + 2 * i][n], T[k0 + 2 * i + 1][n]);
    uint4* dst = (uint4*)(Wt + (size_t)(nb + n) * K + kb + k0);
    dst[0] = make_uint4(pk[0], pk[1], pk[2], pk[3]);
    dst[1] = make_uint4(pk[4], pk[5], pk[6], pk[7]);
}

// x fp32 -> bf16 (8 elems/thread)
__global__ __launch_bounds__(256)
void k_f2b(const float* __restrict__ x, u16* __restrict__ xb)
{
    const int g = blockIdx.x * 256 + threadIdx.x;
    const float4* s = (const float4*)(x + (size_t)g * 8);
    float4 a = s[0], c = s[1];
    u32 pk[4] = {
        (u32)f2b(a.x) | ((u32)f2b(a.y) << 16), (u32)f2b(a.z) | ((u32)f2b(a.w) << 16),
        (u32)f2b(c.x) | ((u32)f2b(c.y) << 16), (u32)f2b(c.z) | ((u32)f2b(c.w) << 16)};
    *(uint4*)(xb + (size_t)g * 8) = make_uint4(pk[0], pk[1], pk[2], pk[3]);
}

// ---------------------------------------------------------------------------
extern "C" void kernel_launch(void* const* d_in, const int* in_sizes, int n_in,
                              void* d_out, int out_size, void* d_ws, size_t ws_size,
                              hipStream_t stream)
{
    const float* x    = (const float*)d_in[0];
    const float* Win  = (const float*)d_in[1];
    const float* bin_ = (const float*)d_in[2];
    const float* Wqkv = (const float*)d_in[3];
    const float* bqkv = (const float*)d_in[4];
    const float* Wo   = (const float*)d_in[5];
    const float* bo   = (const float*)d_in[6];
    const float* ln1g = (const float*)d_in[7];
    const float* ln1b = (const float*)d_in[8];
    const float* Wf1  = (const float*)d_in[9];
    const float* bf1  = (const float*)d_in[10];
    const float* Wf2  = (const float*)d_in[11];
    const float* bf2  = (const float*)d_in[12];
    const float* ln2g = (const float*)d_in[13];
    const float* ln2b = (const float*)d_in[14];
    const float* lnfg = (const float*)d_in[15];
    const float* lnfb = (const float*)d_in[16];
    const float* Wout = (const float*)d_in[17];
    const float* bout = (const float*)d_in[18];
    float* out = (float*)d_out;

    const int M = 4096;
    char* ws = (char*)d_ws;
    float* h    = (float*)(ws + 0);                 //  8 MB  fp32 residual
    u16*   y    = (u16*)(ws + 8388608);             //  4 MB  bf16 LN/attn out
    u16*   big  = (u16*)(ws + 12582912);            // 16 MB  bf16 qkv/ff1
    u16*   Kf   = (u16*)(ws + 29360128);            //  4 MB  K frag-native
    u16*   Vf   = (u16*)(ws + 33554432);            //  4 MB  V frag-native
    u16*   xb   = big;                              //  aliased: only used pre-layer0
    u16*   WinT  = (u16*)(ws + 37748736);           //  128 KB
    u16*   WoutT = (u16*)(ws + 37879808);           //  128 KB
    u16*   WqkvT = (u16*)(ws + 38010880);           //  4 x 1.5 MB
    u16*   WoT   = (u16*)(ws + 44302336);           //  4 x 0.5 MB
    u16*   Wf1T  = (u16*)(ws + 46399488);           //  4 x 2 MB
    u16*   Wf2T  = (u16*)(ws + 54788096);           //  4 x 2 MB (ends ~63 MB)

    dim3 blk(256);

    k_f2b<<<256, blk, 0, stream>>>(x, xb);
    k_wt_all<<<3104, blk, 0, stream>>>(Wqkv, Wo, Wf1, Wf2, Win, Wout,
                                       WqkvT, WoT, Wf1T, Wf2T, WinT, WoutT);

    // input projection + sinusoidal PE -> h (fp32); xb aliases big
    k_gemm_mfma<EPI_PE, 64, 64><<<dim3(8, 64), blk, 0, stream>>>(
        xb, WinT, bin_, nullptr, h, nullptr, nullptr, M, 512, 128);

    for (int lyr = 0; lyr < 4; ++lyr) {
        k_ln<<<1024, blk, 0, stream>>>(h, ln1g + lyr * 512, ln1b + lyr * 512, y);
        k_gemm_mfma<EPI_QKV, 64, 128><<<dim3(12, 64), blk, 0, stream>>>(
            y, WqkvT + (size_t)lyr * 512 * 1536, bqkv + lyr * 1536, nullptr,
            big, Kf, Vf, M, 1536, 512);
        k_attn<<<1024, blk, 0, stream>>>(big, Kf, Vf, y);
        k_gemm_mfma<EPI_RES, 64, 64><<<dim3(8, 64), blk, 0, stream>>>(
            y, WoT + (size_t)lyr * 512 * 512, bo + lyr * 512, h, h, nullptr, nullptr, M, 512, 512);
        k_ln<<<1024, blk, 0, stream>>>(h, ln2g + lyr * 512, ln2b + lyr * 512, y);
        k_gemm_mfma<EPI_GELU, 64, 128><<<dim3(16, 64), blk, 0, stream>>>(
            y, Wf1T + (size_t)lyr * 512 * 2048, bf1 + lyr * 2048, nullptr,
            big, nullptr, nullptr, M, 2048, 512);
        k_gemm_mfma<EPI_RES, 64, 64><<<dim3(8, 64), blk, 0, stream>>>(
            big, Wf2T + (size_t)lyr * 2048 * 512, bf2 + lyr * 512, h, h, nullptr, nullptr, M, 512, 2048);
    }

    k_ln<<<1024, blk, 0, stream>>>(h, lnfg, lnfb, y);
    k_gemm_mfma<EPI_OUTF, 64, 64><<<dim3(2, 64), blk, 0, stream>>>(
        y, WoutT, bout, nullptr, out, nullptr, nullptr, M, 128, 512);
}

// Round 19
// 413.406 us; speedup vs baseline: 1.1897x; 1.1897x over previous
//
#include <hip/hip_runtime.h>
#include <math.h>
#include <type_traits>
#include <utility>

#define TT 2048
typedef unsigned short u16;
typedef unsigned int u32;
typedef float f32x4 __attribute__((ext_vector_type(4)));
typedef float f32x16 __attribute__((ext_vector_type(16)));
typedef short s16x8 __attribute__((ext_vector_type(8)));
typedef __bf16 bf16x8 __attribute__((ext_vector_type(8)));
typedef __bf16 bf16x2 __attribute__((ext_vector_type(2)));
typedef u32 u32x4 __attribute__((ext_vector_type(4)));

#define L2E8 0.1803368801111731f   // 0.125 * log2(e)
#define EXP2(x) __builtin_amdgcn_exp2f(x)   // raw v_exp_f32 (glibc-macro-safe)

enum { EPI_PE = 0, EPI_QKV = 1, EPI_RES = 2, EPI_GELU = 3, EPI_OUTF = 4 };

// ---- MFMA wrappers: handle either builtin signature (v8i16 or v8bf16) ----
template<typename V, typename = void> struct mfma32_takes : std::false_type {};
template<typename V> struct mfma32_takes<V, std::void_t<decltype(
    __builtin_amdgcn_mfma_f32_32x32x16_bf16(std::declval<V>(), std::declval<V>(),
                                            std::declval<f32x16>(), 0, 0, 0))>>
    : std::true_type {};

template<typename VA>
__device__ __forceinline__ f32x16 MFMA32(VA a, VA b, f32x16 c) {
    if constexpr (mfma32_takes<VA>::value) {
        return __builtin_amdgcn_mfma_f32_32x32x16_bf16(a, b, c, 0, 0, 0);
    } else {
        return __builtin_amdgcn_mfma_f32_32x32x16_bf16(
            __builtin_bit_cast(bf16x8, a), __builtin_bit_cast(bf16x8, b), c, 0, 0, 0);
    }
}

// fp32 -> bf16 RNE
__device__ __forceinline__ u16 f2b(float f) {
    u32 u = __float_as_uint(f);
    return (u16)((u + 0x7FFFu + ((u >> 16) & 1u)) >> 16);
}

__device__ __forceinline__ u32 pkbf(float a, float b) {
    bf16x2 t; t[0] = (__bf16)a; t[1] = (__bf16)b;
    return __builtin_bit_cast(u32, t);
}

// async global->LDS, 16B per lane; LDS dest = uniform base + lane*16
__device__ __forceinline__ void gload16(const void* g, void* lds_base, int lds_byte_off) {
    __builtin_amdgcn_global_load_lds(
        (const __attribute__((address_space(1))) void*)g,
        (__attribute__((address_space(3))) void*)((char*)lds_base + lds_byte_off),
        16, 0, 0);
}

// gelu via tanh form: max dev ~3e-4 from exact (<< bf16 ulp here)
__device__ __forceinline__ float gelu_f(float v) {
    const float u = v * (1.f + 0.044715f * v * v) * 0.7978845608028654f;
    const float e = EXP2(u * 2.885390081777927f);   // e^{2u}
    const float th = 1.f - 2.f * __builtin_amdgcn_rcpf(e + 1.f);
    return 0.5f * v * (1.f + th);
}

// ---------------------------------------------------------------------------
// bf16 MFMA GEMM (1-phase, 32x32x16 frags): C = A[M,K] @ Bt[N,K]^T + bias.
// XCD-aware block swizzle (T1): work = (p&7)*(nwg/8) + (p>>3) so each XCD's
// L2 owns a contiguous y-range. Bijective since all grids are multiples of 8.
// Tile TM x TN, BK=64, 4 waves (2x2); wave = TM/2 x TN/2 in 32x32 frags.
// C/D map: col=l&31, row=(reg&3)+8*(reg>>2)+4*(l>>5) (m101-verified).
// EPI_QKV: Q cols -> big; K cols -> Kf frag-native; V cols -> LDS-transposed
// into Vf. K/V cols are NOT written to big.
// ---------------------------------------------------------------------------
template<int EPI, int TM, int TN>
__global__ __launch_bounds__(256)
void k_gemm_mfma(const u16* __restrict__ A, const u16* __restrict__ Bt,
                 const float* __restrict__ bias, const float* __restrict__ Rf,
                 void* __restrict__ Cout, u16* __restrict__ Kfp,
                 u16* __restrict__ Vfp, int M, int N, int K)
{
    constexpr int MF = TM / 64;                 // 32x32 m-frags per wave
    constexpr int NF = TN / 64;                 // 32x32 n-frags per wave
    __shared__ __attribute__((aligned(16))) u16 SMEM[TM * 64 + TN * 64];
    u16* As = SMEM;
    u16* Bs = SMEM + TM * 64;
    const int tid = threadIdx.x;
    const int l = tid & 63, wv = tid >> 6;
    const int l31 = l & 31, hi = l >> 5;
    const int wr = wv >> 1, wc = wv & 1;

    // XCD-aware swizzle of the linear block id
    const int gx = gridDim.x;
    const int nwg = gx * gridDim.y;
    int bid = blockIdx.y * gx + blockIdx.x;
    if ((nwg & 7) == 0) bid = (bid & 7) * (nwg >> 3) + (bid >> 3);
    const int bxi = bid % gx, byi = bid / gx;
    const int row0 = byi * TM, col0 = bxi * TN;

    f32x16 acc[MF][NF] = {};

    for (int kt = 0; kt < K; kt += 64) {
#pragma unroll
        for (int i = 0; i < TM / 32; ++i) {          // A: TM*8 chunks of 16B
            const int u = i * 256 + wv * 64 + l;
            const int ar = u >> 3, ac = u & 7;
            const int sc = (ac ^ (ar & 7)) << 3;     // source chunk *8 elems
            const int off = __builtin_amdgcn_readfirstlane((i * 256 + wv * 64) * 16);
            gload16(A + (size_t)(row0 + ar) * K + kt + sc, As, off);
        }
#pragma unroll
        for (int i = 0; i < TN / 32; ++i) {          // B: TN*8 chunks
            const int u = i * 256 + wv * 64 + l;
            const int ar = u >> 3, ac = u & 7;
            const int sc = (ac ^ (ar & 7)) << 3;
            const int off = __builtin_amdgcn_readfirstlane((i * 256 + wv * 64) * 16);
            gload16(Bt + (size_t)(col0 + ar) * K + kt + sc, Bs, off);
        }
        __syncthreads();
        s16x8 af[MF][4], bf[NF][4];
#pragma unroll
        for (int m = 0; m < MF; ++m) {
            const int r = wr * (TM / 2) + m * 32 + l31;
#pragma unroll
            for (int kk = 0; kk < 4; ++kk)
                af[m][kk] = *(const s16x8*)(As + r * 64 + (((kk * 2 + hi) ^ (r & 7)) << 3));
        }
#pragma unroll
        for (int n = 0; n < NF; ++n) {
            const int r = wc * (TN / 2) + n * 32 + l31;
#pragma unroll
            for (int kk = 0; kk < 4; ++kk)
                bf[n][kk] = *(const s16x8*)(Bs + r * 64 + (((kk * 2 + hi) ^ (r & 7)) << 3));
        }
#pragma unroll
        for (int kk = 0; kk < 4; ++kk)
#pragma unroll
            for (int m = 0; m < MF; ++m)
#pragma unroll
                for (int n = 0; n < NF; ++n)
                    acc[m][n] = MFMA32(af[m][kk], bf[n][kk], acc[m][n]);
        __syncthreads();
    }

    if constexpr (EPI == EPI_QKV) {
        if (col0 < 512) {
            // ---- Q region: bf16 to big
#pragma unroll
            for (int m = 0; m < MF; ++m)
#pragma unroll
                for (int r = 0; r < 16; ++r) {
                    const int row = row0 + wr * (TM / 2) + m * 32 + (r & 3) + 8 * (r >> 2) + 4 * hi;
#pragma unroll
                    for (int n = 0; n < NF; ++n) {
                        const int col = col0 + wc * (TN / 2) + n * 32 + l31;
                        ((u16*)Cout)[(size_t)row * N + col] = f2b(acc[m][n][r] + bias[col]);
                    }
                }
        } else if (col0 < 1024) {
            // ---- K region: frag-native Kf direct
#pragma unroll
            for (int m = 0; m < MF; ++m)
#pragma unroll
                for (int r = 0; r < 16; ++r) {
                    const int row = row0 + wr * (TM / 2) + m * 32 + (r & 3) + 8 * (r >> 2) + 4 * hi;
                    const int t = row & (TT - 1), bb = row >> 11;
#pragma unroll
                    for (int n = 0; n < NF; ++n) {
                        const int col = col0 + wc * (TN / 2) + n * 32 + l31;
                        const int dd = col - 512;
                        const int hh = dd >> 6, c = (dd >> 3) & 7, j = dd & 7;
                        Kfp[(((size_t)(bb * 8 + hh) * 8 + c) * 2048 + t) * 8 + j]
                            = f2b(acc[m][n][r] + bias[col]);
                    }
                }
        } else {
            // ---- V region: transpose via LDS -> Vf (coalesced uint4)
            u16* TV = SMEM;                      // [64][128], reuse staging LDS
#pragma unroll
            for (int m = 0; m < MF; ++m)
#pragma unroll
                for (int r = 0; r < 16; ++r) {
                    const int rr = wr * (TM / 2) + m * 32 + (r & 3) + 8 * (r >> 2) + 4 * hi;
#pragma unroll
                    for (int n = 0; n < NF; ++n) {
                        const int cc_ = wc * (TN / 2) + n * 32 + l31;
                        TV[rr * 128 + cc_] = f2b(acc[m][n][r] + bias[col0 + cc_]);
                    }
                }
            __syncthreads();
            const int gt = (row0 & (TT - 1)) >> 6, bb = row0 >> 11;
            const int hh0 = (col0 - 1024) >> 6;
#pragma unroll
            for (int i = 0; i < 4; ++i) {
                const int u = i * 256 + tid;
                const int hsel = u >> 9, rem = u & 511;
                const int cc = rem >> 6, d = rem & 63;
                u32 pk[4];
#pragma unroll
                for (int jp = 0; jp < 4; ++jp)
                    pk[jp] = (u32)TV[(cc * 8 + 2 * jp) * 128 + hsel * 64 + d]
                           | ((u32)TV[(cc * 8 + 2 * jp + 1) * 128 + hsel * 64 + d] << 16);
                *(uint4*)(Vfp + ((((size_t)(bb * 8 + hh0 + hsel) * 32 + gt) * 8 + cc) * 64 + d) * 8)
                    = make_uint4(pk[0], pk[1], pk[2], pk[3]);
            }
        }
        return;
    }

#pragma unroll
    for (int m = 0; m < MF; ++m)
#pragma unroll
        for (int r = 0; r < 16; ++r) {
            const int row = row0 + wr * (TM / 2) + m * 32 + (r & 3) + 8 * (r >> 2) + 4 * hi;
#pragma unroll
            for (int n = 0; n < NF; ++n) {
                const int col = col0 + wc * (TN / 2) + n * 32 + l31;
                float v = acc[m][n][r] + bias[col];
                const size_t idx = (size_t)row * N + col;
                if constexpr (EPI == EPI_PE) {
                    const int t = row & (TT - 1);
                    const float freq = __expf(-(float)(col & ~1) * 0.017988946039015984f);
                    const float ang = (float)t * freq;
                    v += (col & 1) ? cosf(ang) : sinf(ang);
                    ((float*)Cout)[idx] = v;
                } else if constexpr (EPI == EPI_GELU) {
                    ((u16*)Cout)[idx] = f2b(gelu_f(v));
                } else if constexpr (EPI == EPI_RES) {
                    ((float*)Cout)[idx] = Rf[idx] + v;
                } else {
                    ((float*)Cout)[idx] = v;
                }
            }
        }
}

// ---------------------------------------------------------------------------
// LayerNorm D=512: h(fp32) -> y(bf16). One wave per row.
// ---------------------------------------------------------------------------
__global__ __launch_bounds__(256)
void k_ln(const float* __restrict__ X, const float* __restrict__ g,
          const float* __restrict__ b, u16* __restrict__ Y)
{
    const int lane = threadIdx.x & 63;
    const int row = blockIdx.x * 4 + (threadIdx.x >> 6);
    const float* x = X + (size_t)row * 512 + lane * 8;

    float4 v0 = *(const float4*)x;
    float4 v1 = *(const float4*)(x + 4);
    float vals[8] = {v0.x, v0.y, v0.z, v0.w, v1.x, v1.y, v1.z, v1.w};

    float s = 0.f;
#pragma unroll
    for (int i = 0; i < 8; ++i) s += vals[i];
#pragma unroll
    for (int off = 32; off >= 1; off >>= 1) s += __shfl_xor(s, off);
    const float mu = s * (1.f / 512.f);

    float sq = 0.f;
#pragma unroll
    for (int i = 0; i < 8; ++i) { float d = vals[i] - mu; sq += d * d; }
#pragma unroll
    for (int off = 32; off >= 1; off >>= 1) sq += __shfl_xor(sq, off);
    const float rs = rsqrtf(sq * (1.f / 512.f) + 1e-5f);

    const float* gp = g + lane * 8;
    const float* bp = b + lane * 8;
    float4 g0 = *(const float4*)gp, g1 = *(const float4*)(gp + 4);
    float4 b0 = *(const float4*)bp, b1 = *(const float4*)(bp + 4);
    float ga[8] = {g0.x, g0.y, g0.z, g0.w, g1.x, g1.y, g1.z, g1.w};
    float bb[8] = {b0.x, b0.y, b0.z, b0.w, b1.x, b1.y, b1.z, b1.w};

    u32 pk[4];
#pragma unroll
    for (int i = 0; i < 4; ++i) {
        float a0 = (vals[2 * i]     - mu) * rs * ga[2 * i]     + bb[2 * i];
        float a1 = (vals[2 * i + 1] - mu) * rs * ga[2 * i + 1] + bb[2 * i + 1];
        pk[i] = (u32)f2b(a0) | ((u32)f2b(a1) << 16);
    }
    *(uint4*)(Y + (size_t)row * 512 + lane * 8) = make_uint4(pk[0], pk[1], pk[2], pk[3]);
}

// ---------------------------------------------------------------------------
// Causal flash attention, in-block split-KV, FRAGMENT-NATIVE K/V loads.
// exp2-folded softmax + setprio around MFMA clusters. (r17 verbatim.)
// ---------------------------------------------------------------------------
__global__ __launch_bounds__(256, 4)
void k_attn(const u16* __restrict__ qkv, const u16* __restrict__ Kf,
            const u16* __restrict__ Vf, u16* __restrict__ y)
{
    __shared__ float Om[4][32 * 65];     // [wave][q*65 + d]
    __shared__ float Ml[4][32][2];       // [wave][q][{m,l}]
    const int tid = threadIdx.x;
    const int l = tid & 63, w = tid >> 6;
    const int l31 = l & 31, hi = l >> 5;
    const int bx = blockIdx.x;
    const int xcd = bx & 7, s = bx >> 3;
    const int bh = xcd * 2 + (s & 1);
    const int t_tile = 63 - (s >> 1);
    const int b = bh >> 3, hh = bh & 7;
    const int bT = b * TT, hh64 = hh * 64;

    const int qg = t_tile * 32 + l31;
    const int NT = (t_tile >> 1) + 1;    // kv tiles (64-wide) this q-tile needs

    f32x16 o[2] = {};
    float m = -1e30f, lsum = 0.f;

    if (w < NT) {
        // Q B-frags (scattered, but once per wave)
        s16x8 qf[4];
        {
            const u16* qsrc = qkv + (size_t)(bT + qg) * 1536 + hh64 + hi * 8;
#pragma unroll
            for (int dk = 0; dk < 4; ++dk) qf[dk] = *(const s16x8*)(qsrc + dk * 16);
        }
        const u16* kfb = Kf + ((size_t)bh * 8 + hi) * 2048 * 8;
        const u16* vfb = Vf + (((size_t)bh * 32) * 8 + hi) * 64 * 8;

        for (int g = w; g < NT; g += 4) {
            // K frags: coalesced 16B/lane
            s16x8 kf[8];
#pragma unroll
            for (int nb = 0; nb < 2; ++nb)
#pragma unroll
                for (int dk = 0; dk < 4; ++dk)
                    kf[nb * 4 + dk] = *(const s16x8*)(
                        kfb + ((size_t)(dk * 2) * 2048 + g * 64 + nb * 32 + l31) * 8);

            // S^T = K Q^T over d=64
            f32x16 sA[2];
            __builtin_amdgcn_s_setprio(1);
#pragma unroll
            for (int nb = 0; nb < 2; ++nb) {
                f32x16 acc = {};
#pragma unroll
                for (int dk = 0; dk < 4; ++dk) acc = MFMA32(kf[nb * 4 + dk], qf[dk], acc);
                sA[nb] = acc;
            }
            __builtin_amdgcn_s_setprio(0);

            // causal mask on the diagonal supertile
            if (g == NT - 1) {
                const int kvb = g * 64, hi4 = hi * 4;
#pragma unroll
                for (int nb = 0; nb < 2; ++nb)
#pragma unroll
                    for (int r = 0; r < 16; ++r) {
                        const int kv = kvb + nb * 32 + (r & 3) + 8 * (r >> 2) + hi4;
                        sA[nb][r] = (kv > qg) ? -1e30f : sA[nb][r];
                    }
            }

            // online softmax (scale*log2e folded into exp2), exact defer-max
            float tmp[16];
#pragma unroll
            for (int r = 0; r < 16; ++r) tmp[r] = fmaxf(sA[0][r], sA[1][r]);
#pragma unroll
            for (int st = 8; st >= 1; st >>= 1)
#pragma unroll
                for (int r = 0; r < 8; ++r)
                    if (r < st) tmp[r] = fmaxf(tmp[r], tmp[r + st]);
            float mt = fmaxf(tmp[0], __shfl_xor(tmp[0], 32));
            const bool grow = !__all(mt <= m);
            if (grow) {
                const float mn = fmaxf(m, mt);
                const float alpha = EXP2((m - mn) * L2E8);
                m = mn;
                lsum *= alpha;
#pragma unroll
                for (int dt = 0; dt < 2; ++dt)
#pragma unroll
                    for (int r = 0; r < 16; ++r) o[dt][r] *= alpha;
            }
            const float mc = -m * L2E8;

            float p[2][16];
            float sum[16];
#pragma unroll
            for (int r = 0; r < 16; ++r) {
                p[0][r] = EXP2(fmaf(sA[0][r], L2E8, mc));
                p[1][r] = EXP2(fmaf(sA[1][r], L2E8, mc));
                sum[r] = p[0][r] + p[1][r];
            }
#pragma unroll
            for (int st = 8; st >= 1; st >>= 1)
#pragma unroll
                for (int r = 0; r < 8; ++r)
                    if (r < st) sum[r] += sum[r + st];
            float psum = sum[0] + __shfl_xor(sum[0], 32);
            lsum += psum;

            // P (f32, D-layout) -> bf16 A-frags via lane<->lane+32 exchange
            u32 pk2[2][8], sw2[2][8];
#pragma unroll
            for (int nb = 0; nb < 2; ++nb)
#pragma unroll
                for (int i = 0; i < 8; ++i) {
                    pk2[nb][i] = pkbf(p[nb][2 * i], p[nb][2 * i + 1]);
                    sw2[nb][i] = __shfl_xor(pk2[nb][i], 32);
                }
            s16x8 pa[4];
#pragma unroll
            for (int nb = 0; nb < 2; ++nb)
#pragma unroll
                for (int k16 = 0; k16 < 2; ++k16) {
                    const int i0 = k16 * 4;
                    u32 w0 = hi ? sw2[nb][i0 + 2] : pk2[nb][i0 + 0];
                    u32 w1 = hi ? sw2[nb][i0 + 3] : pk2[nb][i0 + 1];
                    u32 w2 = hi ? pk2[nb][i0 + 2] : sw2[nb][i0 + 0];
                    u32 w3 = hi ? pk2[nb][i0 + 3] : sw2[nb][i0 + 1];
                    u32x4 t4 = {w0, w1, w2, w3};
                    pa[nb * 2 + k16] = __builtin_bit_cast(s16x8, t4);
                }

            // O^T += V^T P^T, V frags coalesced 16B/lane
            __builtin_amdgcn_s_setprio(1);
#pragma unroll
            for (int dt = 0; dt < 2; ++dt) {
                f32x16 acc = o[dt];
#pragma unroll
                for (int ks = 0; ks < 4; ++ks)
                    acc = MFMA32(*(const s16x8*)(
                        vfb + (((size_t)g * 8 + ks * 2) * 64 + dt * 32 + l31) * 8),
                        pa[ks], acc);
                o[dt] = acc;
            }
            __builtin_amdgcn_s_setprio(0);
        }
    }

    // ---- dump partials: lane q = l31, d = dt*32 + (r&3)+8*(r>>2)+4*hi
#pragma unroll
    for (int dt = 0; dt < 2; ++dt)
#pragma unroll
        for (int r = 0; r < 16; ++r) {
            const int d = dt * 32 + (r & 3) + 8 * (r >> 2) + 4 * hi;
            Om[w][l31 * 65 + d] = o[dt][r];
        }
    Ml[w][l31][0] = m;
    Ml[w][l31][1] = lsum;
    __syncthreads();

    // ---- combine: thread -> (q = tid&31, d-range (tid>>5)*8 .. +7)
    const int q = tid & 31, d0 = (tid >> 5) * 8;
    float m0 = Ml[0][q][0], m1 = Ml[1][q][0], m2 = Ml[2][q][0], m3 = Ml[3][q][0];
    const float mstar = fmaxf(fmaxf(m0, m1), fmaxf(m2, m3));
    float sc[4];
    sc[0] = EXP2((m0 - mstar) * L2E8);
    sc[1] = EXP2((m1 - mstar) * L2E8);
    sc[2] = EXP2((m2 - mstar) * L2E8);
    sc[3] = EXP2((m3 - mstar) * L2E8);
    const float lstar = sc[0] * Ml[0][q][1] + sc[1] * Ml[1][q][1]
                      + sc[2] * Ml[2][q][1] + sc[3] * Ml[3][q][1];
    float ov[8];
#pragma unroll
    for (int j = 0; j < 8; ++j) ov[j] = 0.f;
#pragma unroll
    for (int ww = 0; ww < 4; ++ww) {
        const float scw = sc[ww];
        const float* src = &Om[ww][q * 65 + d0];
#pragma unroll
        for (int j = 0; j < 8; ++j) ov[j] = fmaf(scw, src[j], ov[j]);
    }
    const float inv = 1.f / lstar;
    u32 pk[4];
#pragma unroll
    for (int i = 0; i < 4; ++i) pk[i] = pkbf(ov[2 * i] * inv, ov[2 * i + 1] * inv);
    u16* yp = y + (size_t)(bT + t_tile * 32 + q) * 512 + hh64 + d0;
    *(uint4*)yp = make_uint4(pk[0], pk[1], pk[2], pk[3]);
}

// ---------------------------------------------------------------------------
// ALL-layer LDS-tiled weight transpose fp32[K][N] -> bf16[N][K], 64x64 tiles.
// One launch: 3072 blocks (4 layers x 768) + 16 Win + 16 Wout = 3104.
// ---------------------------------------------------------------------------
__global__ __launch_bounds__(256)
void k_wt_all(const float* __restrict__ Wqkv, const float* __restrict__ Wo,
              const float* __restrict__ Wf1, const float* __restrict__ Wf2,
              const float* __restrict__ Win, const float* __restrict__ Wout,
              u16* __restrict__ WqkvT, u16* __restrict__ WoT,
              u16* __restrict__ Wf1T, u16* __restrict__ Wf2T,
              u16* __restrict__ WinT, u16* __restrict__ WoutT)
{
    __shared__ float T[64][65];
    const int tid = threadIdx.x;
    int id = blockIdx.x;
    const float* W; u16* Wt; int K, N;
    if (id < 3072) {
        const int lyr = id / 768, sub = id - lyr * 768;
        if (sub < 192)      { W = Wqkv + (size_t)lyr * 512 * 1536; Wt = WqkvT + (size_t)lyr * 512 * 1536; K = 512;  N = 1536; id = sub; }
        else if (sub < 256) { W = Wo   + (size_t)lyr * 512 * 512;  Wt = WoT   + (size_t)lyr * 512 * 512;  K = 512;  N = 512;  id = sub - 192; }
        else if (sub < 512) { W = Wf1  + (size_t)lyr * 512 * 2048; Wt = Wf1T  + (size_t)lyr * 512 * 2048; K = 512;  N = 2048; id = sub - 256; }
        else                { W = Wf2  + (size_t)lyr * 2048 * 512; Wt = Wf2T  + (size_t)lyr * 2048 * 512; K = 2048; N = 512;  id = sub - 512; }
    } else if (id < 3088)   { W = Win;  Wt = WinT;  K = 128; N = 512; id -= 3072; }
    else                    { W = Wout; Wt = WoutT; K = 512; N = 128; id -= 3088; }
    const int nt = N >> 6;
    const int ktile = id / nt, ntile = id - ktile * nt;
    const int kb = ktile * 64, nb = ntile * 64;
#pragma unroll
    for (int i = 0; i < 4; ++i) {
        const int r = i * 16 + (tid >> 4), c = (tid & 15) * 4;
        const float4 v = *(const float4*)&W[(size_t)(kb + r) * N + nb + c];
        T[r][c] = v.x; T[r][c + 1] = v.y; T[r][c + 2] = v.z; T[r][c + 3] = v.w;
    }
    __syncthreads();
    const int n = tid >> 2, k0 = (tid & 3) * 16;
    u32 pk[8];
#pragma unroll
    for (int i = 0; i < 8; ++i)
        pk[i] = pkbf(T[k0 + 2 * i][n], T[k0 + 2 * i + 1][n]);
    uint4* dst = (uint4*)(Wt + (size_t)(nb + n) * K + kb + k0);
    dst[0] = make_uint4(pk[0], pk[1], pk[2], pk[3]);
    dst[1] = make_uint4(pk[4], pk[5], pk[6], pk[7]);
}

// x fp32 -> bf16 (8 elems/thread)
__global__ __launch_bounds__(256)
void k_f2b(const float* __restrict__ x, u16* __restrict__ xb)
{
    const int g = blockIdx.x * 256 + threadIdx.x;
    const float4* s = (const float4*)(x + (size_t)g * 8);
    float4 a = s[0], c = s[1];
    u32 pk[4] = {
        (u32)f2b(a.x) | ((u32)f2b(a.y) << 16), (u32)f2b(a.z) | ((u32)f2b(a.w) << 16),
        (u32)f2b(c.x) | ((u32)f2b(c.y) << 16), (u32)f2b(c.z) | ((u32)f2b(c.w) << 16)};
    *(uint4*)(xb + (size_t)g * 8) = make_uint4(pk[0], pk[1], pk[2], pk[3]);
}

// ---------------------------------------------------------------------------
extern "C" void kernel_launch(void* const* d_in, const int* in_sizes, int n_in,
                              void* d_out, int out_size, void* d_ws, size_t ws_size,
                              hipStream_t stream)
{
    const float* x    = (const float*)d_in[0];
    const float* Win  = (const float*)d_in[1];
    const float* bin_ = (const float*)d_in[2];
    const float* Wqkv = (const float*)d_in[3];
    const float* bqkv = (const float*)d_in[4];
    const float* Wo   = (const float*)d_in[5];
    const float* bo   = (const float*)d_in[6];
    const float* ln1g = (const float*)d_in[7];
    const float* ln1b = (const float*)d_in[8];
    const float* Wf1  = (const float*)d_in[9];
    const float* bf1  = (const float*)d_in[10];
    const float* Wf2  = (const float*)d_in[11];
    const float* bf2  = (const float*)d_in[12];
    const float* ln2g = (const float*)d_in[13];
    const float* ln2b = (const float*)d_in[14];
    const float* lnfg = (const float*)d_in[15];
    const float* lnfb = (const float*)d_in[16];
    const float* Wout = (const float*)d_in[17];
    const float* bout = (const float*)d_in[18];
    float* out = (float*)d_out;

    const int M = 4096;
    char* ws = (char*)d_ws;
    float* h    = (float*)(ws + 0);                 //  8 MB  fp32 residual
    u16*   y    = (u16*)(ws + 8388608);             //  4 MB  bf16 LN/attn out
    u16*   big  = (u16*)(ws + 12582912);            // 16 MB  bf16 qkv/ff1
    u16*   Kf   = (u16*)(ws + 29360128);            //  4 MB  K frag-native
    u16*   Vf   = (u16*)(ws + 33554432);            //  4 MB  V frag-native
    u16*   xb   = big;                              //  aliased: only used pre-layer0
    u16*   WinT  = (u16*)(ws + 37748736);           //  128 KB
    u16*   WoutT = (u16*)(ws + 37879808);           //  128 KB
    u16*   WqkvT = (u16*)(ws + 38010880);           //  4 x 1.5 MB
    u16*   WoT   = (u16*)(ws + 44302336);           //  4 x 0.5 MB
    u16*   Wf1T  = (u16*)(ws + 46399488);           //  4 x 2 MB
    u16*   Wf2T  = (u16*)(ws + 54788096);           //  4 x 2 MB (ends ~63 MB)

    dim3 blk(256);

    k_f2b<<<256, blk, 0, stream>>>(x, xb);
    k_wt_all<<<3104, blk, 0, stream>>>(Wqkv, Wo, Wf1, Wf2, Win, Wout,
                                       WqkvT, WoT, Wf1T, Wf2T, WinT, WoutT);

    // input projection + sinusoidal PE -> h (fp32); xb aliases big
    k_gemm_mfma<EPI_PE, 64, 64><<<dim3(8, 64), blk, 0, stream>>>(
        xb, WinT, bin_, nullptr, h, nullptr, nullptr, M, 512, 128);

    for (int lyr = 0; lyr < 4; ++lyr) {
        k_ln<<<1024, blk, 0, stream>>>(h, ln1g + lyr * 512, ln1b + lyr * 512, y);
        k_gemm_mfma<EPI_QKV, 64, 128><<<dim3(12, 64), blk, 0, stream>>>(
            y, WqkvT + (size_t)lyr * 512 * 1536, bqkv + lyr * 1536, nullptr,
            big, Kf, Vf, M, 1536, 512);
        k_attn<<<1024, blk, 0, stream>>>(big, Kf, Vf, y);
        k_gemm_mfma<EPI_RES, 64, 64><<<dim3(8, 64), blk, 0, stream>>>(
            y, WoT + (size_t)lyr * 512 * 512, bo + lyr * 512, h, h, nullptr, nullptr, M, 512, 512);
        k_ln<<<1024, blk, 0, stream>>>(h, ln2g + lyr * 512, ln2b + lyr * 512, y);
        k_gemm_mfma<EPI_GELU, 64, 128><<<dim3(16, 64), blk, 0, stream>>>(
            y, Wf1T + (size_t)lyr * 512 * 2048, bf1 + lyr * 2048, nullptr,
            big, nullptr, nullptr, M, 2048, 512);
        k_gemm_mfma<EPI_RES, 64, 64><<<dim3(8, 64), blk, 0, stream>>>(
            big, Wf2T + (size_t)lyr * 2048 * 512, bf2 + lyr * 512, h, h, nullptr, nullptr, M, 512, 2048);
    }

    k_ln<<<1024, blk, 0, stream>>>(h, lnfg, lnfb, y);
    k_gemm_mfma<EPI_OUTF, 64, 64><<<dim3(2, 64), blk, 0, stream>>>(
        y, WoutT, bout, nullptr, out, nullptr, nullptr, M, 128, 512);
}